// Round 9
// baseline (184.228 us; speedup 1.0000x reference)
//
#include <hip/hip_runtime.h>
#include <math.h>

#define BATCH 8192
#define NU 512      // NUM_UNITS
#define NIN 256     // NUM_IN

typedef __attribute__((ext_vector_type(8))) __bf16 bf16x8;
typedef __attribute__((ext_vector_type(4))) float f32x4;

__device__ __forceinline__ float2 cmul(float2 a, float2 b){
    return make_float2(a.x*b.x - a.y*b.y, a.x*b.y + a.y*b.x);
}
__device__ __forceinline__ float2 cadd(float2 a, float2 b){ return make_float2(a.x+b.x, a.y+b.y); }
__device__ __forceinline__ float2 csub(float2 a, float2 b){ return make_float2(a.x-b.x, a.y-b.y); }

// cis(sign * 2*pi*idx/512); idx in [0,256)
template<bool INV>
__device__ __forceinline__ float2 twid512(int idx){
    float ang = 0.012271846303085129f * (float)idx;   // 2*pi/512
    float sn, cs; __sincosf(INV ? ang : -ang, &sn, &cs);
    return make_float2(cs, sn);
}

// ---- XOR-lane exchange, DS-pipe-minimized --------------------------------
// h=1,2: DPP quad_perm; h=8: DPP row_ror:8 (+8 == -8 mod 16);
// h=4,16: ds_swizzle BitMode xor patterns (guide-verified 0x101F / 0x401F);
// h=32: __builtin_amdgcn_permlane32_swap (distinct SSA outputs — no aliasing)
//       + XOR disambiguation: exactly one output equals own value, so
//       partner = res0 ^ res1 ^ own (exact, polarity-proof).
template<int H>
__device__ __forceinline__ float lane_xor(float x, int l){
    unsigned u = __float_as_uint(x);
    unsigned r;
    if constexpr (H == 1){
        r = (unsigned)__builtin_amdgcn_mov_dpp((int)u, 0xB1, 0xF, 0xF, false);  // quad [1,0,3,2]
    } else if constexpr (H == 2){
        r = (unsigned)__builtin_amdgcn_mov_dpp((int)u, 0x4E, 0xF, 0xF, false);  // quad [2,3,0,1]
    } else if constexpr (H == 4){
        r = (unsigned)__builtin_amdgcn_ds_swizzle((int)u, 0x101F);              // lane^4
    } else if constexpr (H == 8){
        r = (unsigned)__builtin_amdgcn_mov_dpp((int)u, 0x128, 0xF, 0xF, false); // row_ror:8
    } else if constexpr (H == 16){
        r = (unsigned)__builtin_amdgcn_ds_swizzle((int)u, 0x401F);              // lane^16
    } else {  // H == 32
        auto res = __builtin_amdgcn_permlane32_swap((unsigned)u, (unsigned)u, false, false);
        r = ((unsigned)res[0]) ^ ((unsigned)res[1]) ^ u;
    }
    return __uint_as_float(r);
}

// pack two f32 -> two bf16 (RNE) in one uint
__device__ __forceinline__ unsigned int pack2bf(float x, float y){
    unsigned int ux = __float_as_uint(x);
    ux = (ux + 0x7FFFu + ((ux >> 16) & 1u)) >> 16;
    unsigned int uy = __float_as_uint(y);
    uy = (uy + 0x7FFFu + ((uy >> 16) & 1u)) & 0xFFFF0000u;
    return ux | uy;
}

// ---------------- Kernel A: P = inputs @ w_ih^T via bf16 MFMA -------------
// (unchanged)

__device__ __forceinline__ void stage_tile(const float* __restrict__ G,
                                           char* __restrict__ lds,
                                           int kb, int tid){
    const int r0 = tid >> 3;          // 0..31
    const int kc = (tid & 7) << 3;    // 0..56, 8 floats per thread
    #pragma unroll
    for (int it = 0; it < 4; ++it){
        const int row = r0 + (it << 5);
        const float* g = G + (size_t)row * NIN + kb + kc;
        float4 v0 = *(const float4*)g;
        float4 v1 = *(const float4*)(g + 4);
        int4 w;
        w.x = (int)pack2bf(v0.x, v0.y);
        w.y = (int)pack2bf(v0.z, v0.w);
        w.z = (int)pack2bf(v1.x, v1.y);
        w.w = (int)pack2bf(v1.z, v1.w);
        int off = (row << 7) + (kc << 1);   // row*128B + kc*2B
        off ^= (row & 7) << 4;              // XOR swizzle
        *(int4*)(lds + off) = w;
    }
}

__global__ __launch_bounds__(256) void gemm_bf16(const float* __restrict__ A,
                                                 const float* __restrict__ W,
                                                 float* __restrict__ P){
    __shared__ __align__(16) char smem[2 * 128*64*2];   // 32 KiB
    char* As = smem;
    char* Bs = smem + 128*64*2;
    const int tid  = threadIdx.x;
    const int lane = tid & 63, wv = tid >> 6;
    const int wm = wv >> 1, wn = wv & 1;     // 2x2 wave grid, 64x64 each
    const int bm = blockIdx.y, bn = blockIdx.x;

    const float* Ag = A + (size_t)bm * 128 * NIN;
    const float* Wg = W + (size_t)bn * 128 * NIN;

    f32x4 acc[4][4] = {};
    const int frow = lane & 15;
    const int kq   = (lane >> 4) << 4;       // byte offset of 8-bf16 k-group

    for (int kb = 0; kb < NIN; kb += 64){
        if (kb) __syncthreads();
        stage_tile(Ag, As, kb, tid);
        stage_tile(Wg, Bs, kb, tid);
        __syncthreads();
        #pragma unroll
        for (int ks = 0; ks < 2; ++ks){
            const int koff = kq + (ks << 6);
            bf16x8 a[4], b[4];
            #pragma unroll
            for (int i = 0; i < 4; ++i){
                const int ar = wm*64 + i*16 + frow;
                a[i] = *(const bf16x8*)(As + (((ar << 7) + koff) ^ ((ar & 7) << 4)));
                const int br = wn*64 + i*16 + frow;
                b[i] = *(const bf16x8*)(Bs + (((br << 7) + koff) ^ ((br & 7) << 4)));
            }
            #pragma unroll
            for (int mi = 0; mi < 4; ++mi)
                #pragma unroll
                for (int ni = 0; ni < 4; ++ni)
                    acc[mi][ni] = __builtin_amdgcn_mfma_f32_16x16x32_bf16(
                        a[mi], b[ni], acc[mi][ni], 0, 0, 0);
        }
    }

    // epilogue: stage 32-row quarters through LDS for coalesced float4 writes.
    float* stg = (float*)smem;
    const int lr4 = (lane >> 4) << 2;
    #pragma unroll
    for (int q = 0; q < 4; ++q){
        __syncthreads();            // previous users of smem done
        if (wm == (q >> 1)){
            const int miBase = (q & 1) * 2;
            #pragma unroll
            for (int mj = 0; mj < 2; ++mj)
                #pragma unroll
                for (int ni = 0; ni < 4; ++ni)
                    #pragma unroll
                    for (int r = 0; r < 4; ++r)
                        stg[(lr4 + mj*16 + r)*132 + wn*64 + ni*16 + frow]
                            = acc[miBase + mj][ni][r];
        }
        __syncthreads();
        #pragma unroll
        for (int it = 0; it < 4; ++it){
            int idx = it*256 + tid;       // 0..1023: 32 rows x 32 float4
            int r32 = idx >> 5;
            int c4  = idx & 31;
            float4 v = *(const float4*)(stg + r32*132 + c4*4);
            int grow = bm*128 + (q >> 1)*64 + (q & 1)*32 + r32;
            *(float4*)(P + (size_t)grow*1024 + bn*128 + c4*4) = v;
        }
    }
}

// ---------------- Kernel B: wave-per-row URNN pipeline --------------------

template<int H>
__device__ __forceinline__ void fwd_stage(float2 z[8], int l){
    constexpr int M = 256 / H;
    float2 w = twid512<false>(M * (l & (H-1)));
    const bool hi = (l & H) != 0;
    #pragma unroll
    for (int r = 0; r < 8; ++r){
        float2 p;
        p.x = lane_xor<H>(z[r].x, l);
        p.y = lane_xor<H>(z[r].y, l);
        z[r] = hi ? cmul(w, csub(p, z[r])) : cadd(z[r], p);
    }
}

template<int H>
__device__ __forceinline__ void inv_stage(float2 z[8], int l){
    constexpr int M = 256 / H;
    float2 w = twid512<true>(M * (l & (H-1)));
    const bool hi = (l & H) != 0;
    #pragma unroll
    for (int r = 0; r < 8; ++r){
        float2 p;
        p.x = lane_xor<H>(z[r].x, l);
        p.y = lane_xor<H>(z[r].y, l);
        float2 t = cmul(w, hi ? z[r] : p);
        z[r] = hi ? csub(p, t) : cadd(z[r], t);
    }
}

__device__ __forceinline__ void fft_fwd(float2 z[8], int l){
    #pragma unroll
    for (int r = 0; r < 4; ++r){
        float2 w = twid512<false>(r*64 + l);
        float2 a = z[r], b = z[r+4];
        z[r]   = cadd(a, b);
        z[r+4] = cmul(w, csub(a, b));
    }
    {
        float2 w0 = twid512<false>(2*l), w1 = twid512<false>(2*(64+l));
        const int gs[4] = {0,1,4,5};
        #pragma unroll
        for (int k = 0; k < 4; ++k){
            int g = gs[k];
            float2 w = (g & 1) ? w1 : w0;
            float2 a = z[g], b = z[g+2];
            z[g]   = cadd(a, b);
            z[g+2] = cmul(w, csub(a, b));
        }
    }
    {
        float2 w = twid512<false>(4*l);
        #pragma unroll
        for (int g = 0; g < 8; g += 2){
            float2 a = z[g], b = z[g+1];
            z[g]   = cadd(a, b);
            z[g+1] = cmul(w, csub(a, b));
        }
    }
    fwd_stage<32>(z, l);
    fwd_stage<16>(z, l);
    fwd_stage<8>(z, l);
    fwd_stage<4>(z, l);
    fwd_stage<2>(z, l);
    fwd_stage<1>(z, l);
}

__device__ __forceinline__ void fft_inv(float2 z[8], int l){
    inv_stage<1>(z, l);
    inv_stage<2>(z, l);
    inv_stage<4>(z, l);
    inv_stage<8>(z, l);
    inv_stage<16>(z, l);
    inv_stage<32>(z, l);
    {
        float2 w = twid512<true>(4*l);
        #pragma unroll
        for (int g = 0; g < 8; g += 2){
            float2 b = cmul(w, z[g+1]);
            z[g+1] = csub(z[g], b);
            z[g]   = cadd(z[g], b);
        }
    }
    {
        float2 w0 = twid512<true>(2*l), w1 = twid512<true>(2*(64+l));
        const int gs[4] = {0,1,4,5};
        #pragma unroll
        for (int k = 0; k < 4; ++k){
            int g = gs[k];
            float2 w = (g & 1) ? w1 : w0;
            float2 b = cmul(w, z[g+2]);
            z[g+2] = csub(z[g], b);
            z[g]   = cadd(z[g], b);
        }
    }
    #pragma unroll
    for (int r = 0; r < 4; ++r){
        float2 w = twid512<true>(r*64 + l);
        float2 b = cmul(w, z[r+4]);
        z[r+4] = csub(z[r], b);
        z[r]   = cadd(z[r], b);
    }
}

__device__ __forceinline__ void wave_reflect(float2 z[8], const float2 v[8], int l){
    float pr = 0.f, pi = 0.f, nn = 0.f;
    #pragma unroll
    for (int r = 0; r < 8; ++r){
        pr += v[r].x*z[r].x + v[r].y*z[r].y;
        pi += v[r].x*z[r].y - v[r].y*z[r].x;
        nn += v[r].x*v[r].x + v[r].y*v[r].y;
    }
    pr += lane_xor<32>(pr, l); pi += lane_xor<32>(pi, l); nn += lane_xor<32>(nn, l);
    pr += lane_xor<16>(pr, l); pi += lane_xor<16>(pi, l); nn += lane_xor<16>(nn, l);
    pr += lane_xor<8>(pr, l);  pi += lane_xor<8>(pi, l);  nn += lane_xor<8>(nn, l);
    pr += lane_xor<4>(pr, l);  pi += lane_xor<4>(pi, l);  nn += lane_xor<4>(nn, l);
    pr += lane_xor<2>(pr, l);  pi += lane_xor<2>(pi, l);  nn += lane_xor<2>(nn, l);
    pr += lane_xor<1>(pr, l);  pi += lane_xor<1>(pi, l);  nn += lane_xor<1>(nn, l);
    float c2 = 2.0f / nn;
    float2 cc = make_float2(c2*pr, c2*pi);
    #pragma unroll
    for (int r = 0; r < 8; ++r)
        z[r] = csub(z[r], cmul(cc, v[r]));
}

__global__ __launch_bounds__(256, 8) void urnn_wave(
        const float* __restrict__ states,
        const float* __restrict__ b_h,
        const float* __restrict__ d1_w,
        const float* __restrict__ r1_re, const float* __restrict__ r1_im,
        const int* __restrict__ perm,
        const float* __restrict__ d2_w,
        const float* __restrict__ r2_re, const float* __restrict__ r2_im,
        const float* __restrict__ d3_w,
        float* __restrict__ out /* in: inputs_mul, out: result */)
{
    __shared__ float2 zbuf[4][512];          // per-wave permutation buffer only

    const int tid = threadIdx.x;
    const int l = tid & 63, wv = tid >> 6;

    const int row = blockIdx.x * 4 + wv;
    const float* srow = states + (size_t)row * 1024;
    float* orow = out + (size_t)row * 1024;

    // preload inputs_mul early
    float2 c[8];
    #pragma unroll
    for (int r = 0; r < 8; ++r) c[r] = ((const float2*)orow)[r*64 + l];

    // state load + diag1 (natural order: storage s = r*64+l holds element s)
    float2 z[8];
    #pragma unroll
    for (int r = 0; r < 8; ++r){
        int e = r*64 + l;
        float2 st = ((const float2*)srow)[e];
        float sn, cs; __sincosf(d1_w[e], &sn, &cs);
        z[r] = cmul(make_float2(cs, sn), st);
    }

    fft_fwd(z, l);                 // -> storage s holds X[rev(s)]

    { // reflection 1 in bit-reversed domain (elementwise => order-free)
        float2 v[8];
        #pragma unroll
        for (int r = 0; r < 8; ++r){
            int i = __brev((unsigned)(r*64 + l)) >> 23;   // rev9(s)
            v[r] = make_float2(r1_re[i], r1_im[i]);
        }
        wave_reflect(z, v, l);
    }

    // permutation + diag2, repacked to bitrev-for-DIT:
    // z'[s] = cis(d2[rev(s)]) * zstore[ rev9(perm[rev(s)]) ]
    {
        float2* zw = zbuf[wv];
        #pragma unroll
        for (int r = 0; r < 8; ++r) zw[r*64 + l] = z[r];
        // no barrier: buffer is private to this wave; compiler orders via lgkmcnt
        #pragma unroll
        for (int r = 0; r < 8; ++r){
            int s = r*64 + l;
            int i = __brev((unsigned)s) >> 23;            // rev9(s)
            int g = __brev((unsigned)perm[i]) >> 23;      // rev9(perm[i])
            float sn, cs; __sincosf(d2_w[i], &sn, &cs);
            z[r] = cmul(make_float2(cs, sn), zw[g]);
        }
    }

    fft_inv(z, l);                 // -> natural order

    { // reflection 2 in natural domain (coalesced global reads)
        float2 v[8];
        #pragma unroll
        for (int r = 0; r < 8; ++r){
            int e = r*64 + l;
            v[r] = make_float2(r2_re[e], r2_im[e]);
        }
        wave_reflect(z, v, l);
    }

    // diag3 * (1/512) + inputs_mul + modReLU; write concat([re, im])
    const float inv = 1.0f/512.0f;
    #pragma unroll
    for (int r = 0; r < 8; ++r){
        int e = r*64 + l;
        float sn, cs; __sincosf(d3_w[e], &sn, &cs);
        float2 zz = cmul(make_float2(cs, sn), z[r]);
        float2 pre = make_float2(c[r].x + zz.x*inv, c[r].y + zz.y*inv);
        float nrm = sqrtf(pre.x*pre.x + pre.y*pre.y);
        float sc = fmaxf(nrm + b_h[e], 0.f) / (nrm + 1e-6f);
        orow[e]       = sc*pre.x;
        orow[e + 512] = sc*pre.y;
    }
}

extern "C" void kernel_launch(void* const* d_in, const int* in_sizes, int n_in,
                              void* d_out, int out_size, void* d_ws, size_t ws_size,
                              hipStream_t stream) {
    const float* inputs = (const float*)d_in[0];
    const float* states = (const float*)d_in[1];
    const float* w_ih   = (const float*)d_in[2];
    const float* b_h    = (const float*)d_in[3];
    const float* d1_w   = (const float*)d_in[4];
    const float* r1_re  = (const float*)d_in[5];
    const float* r1_im  = (const float*)d_in[6];
    const int*   perm   = (const int*)d_in[7];
    const float* d2_w   = (const float*)d_in[8];
    const float* r2_re  = (const float*)d_in[9];
    const float* r2_im  = (const float*)d_in[10];
    const float* d3_w   = (const float*)d_in[11];
    float* out = (float*)d_out;

    dim3 gA(8, 64);   // 1024/128 cols, 8192/128 rows
    gemm_bf16<<<gA, 256, 0, stream>>>(inputs, w_ih, out);
    urnn_wave<<<BATCH/4, 256, 0, stream>>>(states, b_h, d1_w, r1_re, r1_im,
                                           perm, d2_w, r2_re, r2_im, d3_w, out);
}

// Round 11
// 180.776 us; speedup vs baseline: 1.0191x; 1.0191x over previous
//
#include <hip/hip_runtime.h>
#include <math.h>

#define BATCH 8192
#define NU 512      // NUM_UNITS
#define NIN 256     // NUM_IN

typedef __attribute__((ext_vector_type(8))) __bf16 bf16x8;
typedef __attribute__((ext_vector_type(4))) float f32x4;

__device__ __forceinline__ float2 cmul(float2 a, float2 b){
    return make_float2(a.x*b.x - a.y*b.y, a.x*b.y + a.y*b.x);
}
__device__ __forceinline__ float2 cadd(float2 a, float2 b){ return make_float2(a.x+b.x, a.y+b.y); }
__device__ __forceinline__ float2 csub(float2 a, float2 b){ return make_float2(a.x-b.x, a.y-b.y); }

// native cis(x): v_mul+v_fract+v_sin/v_cos instead of accurate ocml sincos
__device__ __forceinline__ float2 cis_native(float ang){
    return make_float2(__cosf(ang), __sinf(ang));
}

// cis(sign * 2*pi*idx/512); idx in [0,256)
template<bool INV>
__device__ __forceinline__ float2 twid512(int idx){
    float ang = 0.012271846303085129f * (float)idx;   // 2*pi/512
    return cis_native(INV ? ang : -ang);
}

// pack two f32 -> two bf16 (RNE) in one uint
__device__ __forceinline__ unsigned int pack2bf(float x, float y){
    unsigned int ux = __float_as_uint(x);
    ux = (ux + 0x7FFFu + ((ux >> 16) & 1u)) >> 16;
    unsigned int uy = __float_as_uint(y);
    uy = (uy + 0x7FFFu + ((uy >> 16) & 1u)) & 0xFFFF0000u;
    return ux | uy;
}

// ---------------- Kernel A: P = inputs @ w_ih^T via bf16 MFMA -------------
// (unchanged)

__device__ __forceinline__ void stage_tile(const float* __restrict__ G,
                                           char* __restrict__ lds,
                                           int kb, int tid){
    const int r0 = tid >> 3;          // 0..31
    const int kc = (tid & 7) << 3;    // 0..56, 8 floats per thread
    #pragma unroll
    for (int it = 0; it < 4; ++it){
        const int row = r0 + (it << 5);
        const float* g = G + (size_t)row * NIN + kb + kc;
        float4 v0 = *(const float4*)g;
        float4 v1 = *(const float4*)(g + 4);
        int4 w;
        w.x = (int)pack2bf(v0.x, v0.y);
        w.y = (int)pack2bf(v0.z, v0.w);
        w.z = (int)pack2bf(v1.x, v1.y);
        w.w = (int)pack2bf(v1.z, v1.w);
        int off = (row << 7) + (kc << 1);   // row*128B + kc*2B
        off ^= (row & 7) << 4;              // XOR swizzle
        *(int4*)(lds + off) = w;
    }
}

__global__ __launch_bounds__(256) void gemm_bf16(const float* __restrict__ A,
                                                 const float* __restrict__ W,
                                                 float* __restrict__ P){
    __shared__ __align__(16) char smem[2 * 128*64*2];   // 32 KiB
    char* As = smem;
    char* Bs = smem + 128*64*2;
    const int tid  = threadIdx.x;
    const int lane = tid & 63, wv = tid >> 6;
    const int wm = wv >> 1, wn = wv & 1;     // 2x2 wave grid, 64x64 each
    const int bm = blockIdx.y, bn = blockIdx.x;

    const float* Ag = A + (size_t)bm * 128 * NIN;
    const float* Wg = W + (size_t)bn * 128 * NIN;

    f32x4 acc[4][4] = {};
    const int frow = lane & 15;
    const int kq   = (lane >> 4) << 4;       // byte offset of 8-bf16 k-group

    for (int kb = 0; kb < NIN; kb += 64){
        if (kb) __syncthreads();
        stage_tile(Ag, As, kb, tid);
        stage_tile(Wg, Bs, kb, tid);
        __syncthreads();
        #pragma unroll
        for (int ks = 0; ks < 2; ++ks){
            const int koff = kq + (ks << 6);
            bf16x8 a[4], b[4];
            #pragma unroll
            for (int i = 0; i < 4; ++i){
                const int ar = wm*64 + i*16 + frow;
                a[i] = *(const bf16x8*)(As + (((ar << 7) + koff) ^ ((ar & 7) << 4)));
                const int br = wn*64 + i*16 + frow;
                b[i] = *(const bf16x8*)(Bs + (((br << 7) + koff) ^ ((br & 7) << 4)));
            }
            #pragma unroll
            for (int mi = 0; mi < 4; ++mi)
                #pragma unroll
                for (int ni = 0; ni < 4; ++ni)
                    acc[mi][ni] = __builtin_amdgcn_mfma_f32_16x16x32_bf16(
                        a[mi], b[ni], acc[mi][ni], 0, 0, 0);
        }
    }

    // epilogue: stage 32-row quarters through LDS for coalesced float4 writes.
    float* stg = (float*)smem;
    const int lr4 = (lane >> 4) << 2;
    #pragma unroll
    for (int q = 0; q < 4; ++q){
        __syncthreads();            // previous users of smem done
        if (wm == (q >> 1)){
            const int miBase = (q & 1) * 2;
            #pragma unroll
            for (int mj = 0; mj < 2; ++mj)
                #pragma unroll
                for (int ni = 0; ni < 4; ++ni)
                    #pragma unroll
                    for (int r = 0; r < 4; ++r)
                        stg[(lr4 + mj*16 + r)*132 + wn*64 + ni*16 + frow]
                            = acc[miBase + mj][ni][r];
        }
        __syncthreads();
        #pragma unroll
        for (int it = 0; it < 4; ++it){
            int idx = it*256 + tid;       // 0..1023: 32 rows x 32 float4
            int r32 = idx >> 5;
            int c4  = idx & 31;
            float4 v = *(const float4*)(stg + r32*132 + c4*4);
            int grow = bm*128 + (q >> 1)*64 + (q & 1)*32 + r32;
            *(float4*)(P + (size_t)grow*1024 + bn*128 + c4*4) = v;
        }
    }
}

// ---------------- Kernel B: wave-per-row URNN pipeline --------------------
// 1 wave = 1 batch row; 512-pt FFT as 64 lanes x 8 regs.
// Exchanges: plain __shfl_xor (round-7 best variant). Trig: native v_sin/v_cos.

__device__ __forceinline__ void fft_fwd(float2 z[8], int l){
    #pragma unroll
    for (int r = 0; r < 4; ++r){
        float2 w = twid512<false>(r*64 + l);
        float2 a = z[r], b = z[r+4];
        z[r]   = cadd(a, b);
        z[r+4] = cmul(w, csub(a, b));
    }
    {
        float2 w0 = twid512<false>(2*l), w1 = twid512<false>(2*(64+l));
        const int gs[4] = {0,1,4,5};
        #pragma unroll
        for (int k = 0; k < 4; ++k){
            int g = gs[k];
            float2 w = (g & 1) ? w1 : w0;
            float2 a = z[g], b = z[g+2];
            z[g]   = cadd(a, b);
            z[g+2] = cmul(w, csub(a, b));
        }
    }
    {
        float2 w = twid512<false>(4*l);
        #pragma unroll
        for (int g = 0; g < 8; g += 2){
            float2 a = z[g], b = z[g+1];
            z[g]   = cadd(a, b);
            z[g+1] = cmul(w, csub(a, b));
        }
    }
    #pragma unroll
    for (int h = 32; h >= 1; h >>= 1){
        int m = 256 / h;
        float2 w = twid512<false>(m * (l & (h-1)));
        bool low = (l & h) != 0;
        #pragma unroll
        for (int r = 0; r < 8; ++r){
            float2 p;
            p.x = __shfl_xor(z[r].x, h);
            p.y = __shfl_xor(z[r].y, h);
            z[r] = low ? cmul(w, csub(p, z[r])) : cadd(z[r], p);
        }
    }
}

__device__ __forceinline__ void fft_inv(float2 z[8], int l){
    #pragma unroll
    for (int h = 1; h <= 32; h <<= 1){
        int m = 256 / h;
        float2 w = twid512<true>(m * (l & (h-1)));
        bool low = (l & h) != 0;
        #pragma unroll
        for (int r = 0; r < 8; ++r){
            float2 p;
            p.x = __shfl_xor(z[r].x, h);
            p.y = __shfl_xor(z[r].y, h);
            float2 t = cmul(w, low ? z[r] : p);
            z[r] = low ? csub(p, t) : cadd(z[r], t);
        }
    }
    {
        float2 w = twid512<true>(4*l);
        #pragma unroll
        for (int g = 0; g < 8; g += 2){
            float2 b = cmul(w, z[g+1]);
            z[g+1] = csub(z[g], b);
            z[g]   = cadd(z[g], b);
        }
    }
    {
        float2 w0 = twid512<true>(2*l), w1 = twid512<true>(2*(64+l));
        const int gs[4] = {0,1,4,5};
        #pragma unroll
        for (int k = 0; k < 4; ++k){
            int g = gs[k];
            float2 w = (g & 1) ? w1 : w0;
            float2 b = cmul(w, z[g+2]);
            z[g+2] = csub(z[g], b);
            z[g]   = cadd(z[g], b);
        }
    }
    #pragma unroll
    for (int r = 0; r < 4; ++r){
        float2 w = twid512<true>(r*64 + l);
        float2 b = cmul(w, z[r+4]);
        z[r+4] = csub(z[r], b);
        z[r]   = cadd(z[r], b);
    }
}

__device__ __forceinline__ void wave_reflect(float2 z[8], const float2 v[8]){
    float pr = 0.f, pi = 0.f, nn = 0.f;
    #pragma unroll
    for (int r = 0; r < 8; ++r){
        pr += v[r].x*z[r].x + v[r].y*z[r].y;
        pi += v[r].x*z[r].y - v[r].y*z[r].x;
        nn += v[r].x*v[r].x + v[r].y*v[r].y;
    }
    #pragma unroll
    for (int off = 32; off > 0; off >>= 1){
        pr += __shfl_xor(pr, off);
        pi += __shfl_xor(pi, off);
        nn += __shfl_xor(nn, off);
    }
    float c2 = 2.0f / nn;
    float2 cc = make_float2(c2*pr, c2*pi);
    #pragma unroll
    for (int r = 0; r < 8; ++r)
        z[r] = csub(z[r], cmul(cc, v[r]));
}

__global__ __launch_bounds__(256, 8) void urnn_wave(
        const float* __restrict__ states,
        const float* __restrict__ b_h,
        const float* __restrict__ d1_w,
        const float* __restrict__ r1_re, const float* __restrict__ r1_im,
        const int* __restrict__ perm,
        const float* __restrict__ d2_w,
        const float* __restrict__ r2_re, const float* __restrict__ r2_im,
        const float* __restrict__ d3_w,
        float* __restrict__ out /* in: inputs_mul, out: result */)
{
    __shared__ float2 zbuf[4][512];          // per-wave permutation buffer only

    const int tid = threadIdx.x;
    const int l = tid & 63, wv = tid >> 6;

    const int row = blockIdx.x * 4 + wv;
    const float* srow = states + (size_t)row * 1024;
    float* orow = out + (size_t)row * 1024;

    // preload inputs_mul early
    float2 c[8];
    #pragma unroll
    for (int r = 0; r < 8; ++r) c[r] = ((const float2*)orow)[r*64 + l];

    // state load + diag1 (natural order: storage s = r*64+l holds element s)
    float2 z[8];
    #pragma unroll
    for (int r = 0; r < 8; ++r){
        int e = r*64 + l;
        float2 st = ((const float2*)srow)[e];
        z[r] = cmul(cis_native(d1_w[e]), st);
    }

    fft_fwd(z, l);                 // -> storage s holds X[rev(s)]

    { // reflection 1 in bit-reversed domain (elementwise => order-free)
        float2 v[8];
        #pragma unroll
        for (int r = 0; r < 8; ++r){
            int i = __brev((unsigned)(r*64 + l)) >> 23;   // rev9(s)
            v[r] = make_float2(r1_re[i], r1_im[i]);
        }
        wave_reflect(z, v);
    }

    // permutation + diag2, repacked to bitrev-for-DIT:
    // z'[s] = cis(d2[rev(s)]) * zstore[ rev9(perm[rev(s)]) ]
    {
        float2* zw = zbuf[wv];
        #pragma unroll
        for (int r = 0; r < 8; ++r) zw[r*64 + l] = z[r];
        // no barrier: buffer is private to this wave; compiler orders via lgkmcnt
        #pragma unroll
        for (int r = 0; r < 8; ++r){
            int s = r*64 + l;
            int i = __brev((unsigned)s) >> 23;            // rev9(s)
            int g = __brev((unsigned)perm[i]) >> 23;      // rev9(perm[i])
            z[r] = cmul(cis_native(d2_w[i]), zw[g]);
        }
    }

    fft_inv(z, l);                 // -> natural order

    { // reflection 2 in natural domain (coalesced global reads)
        float2 v[8];
        #pragma unroll
        for (int r = 0; r < 8; ++r){
            int e = r*64 + l;
            v[r] = make_float2(r2_re[e], r2_im[e]);
        }
        wave_reflect(z, v);
    }

    // diag3 * (1/512) + inputs_mul + modReLU; write concat([re, im])
    const float inv = 1.0f/512.0f;
    #pragma unroll
    for (int r = 0; r < 8; ++r){
        int e = r*64 + l;
        float2 zz = cmul(cis_native(d3_w[e]), z[r]);
        float2 pre = make_float2(c[r].x + zz.x*inv, c[r].y + zz.y*inv);
        float nrm = __builtin_amdgcn_sqrtf(pre.x*pre.x + pre.y*pre.y);
        float sc = fmaxf(nrm + b_h[e], 0.f) / (nrm + 1e-6f);
        orow[e]       = sc*pre.x;
        orow[e + 512] = sc*pre.y;
    }
}

extern "C" void kernel_launch(void* const* d_in, const int* in_sizes, int n_in,
                              void* d_out, int out_size, void* d_ws, size_t ws_size,
                              hipStream_t stream) {
    const float* inputs = (const float*)d_in[0];
    const float* states = (const float*)d_in[1];
    const float* w_ih   = (const float*)d_in[2];
    const float* b_h    = (const float*)d_in[3];
    const float* d1_w   = (const float*)d_in[4];
    const float* r1_re  = (const float*)d_in[5];
    const float* r1_im  = (const float*)d_in[6];
    const int*   perm   = (const int*)d_in[7];
    const float* d2_w   = (const float*)d_in[8];
    const float* r2_re  = (const float*)d_in[9];
    const float* r2_im  = (const float*)d_in[10];
    const float* d3_w   = (const float*)d_in[11];
    float* out = (float*)d_out;

    dim3 gA(8, 64);   // 1024/128 cols, 8192/128 rows
    gemm_bf16<<<gA, 256, 0, stream>>>(inputs, w_ih, out);
    urnn_wave<<<BATCH/4, 256, 0, stream>>>(states, b_h, d1_w, r1_re, r1_im,
                                           perm, d2_w, r2_re, r2_im, d3_w, out);
}

// Round 12
// 165.539 us; speedup vs baseline: 1.1129x; 1.0920x over previous
//
#include <hip/hip_runtime.h>
#include <math.h>

#define BATCH 8192
#define NU 512      // NUM_UNITS
#define NIN 256     // NUM_IN

typedef __attribute__((ext_vector_type(8))) __bf16 bf16x8;
typedef __attribute__((ext_vector_type(4))) float f32x4;

__device__ __forceinline__ float2 cmul(float2 a, float2 b){
    return make_float2(a.x*b.x - a.y*b.y, a.x*b.y + a.y*b.x);
}
__device__ __forceinline__ float2 cadd(float2 a, float2 b){ return make_float2(a.x+b.x, a.y+b.y); }
__device__ __forceinline__ float2 csub(float2 a, float2 b){ return make_float2(a.x-b.x, a.y-b.y); }

__device__ __forceinline__ float2 cis_native(float ang){
    return make_float2(__cosf(ang), __sinf(ang));
}
template<bool INV>
__device__ __forceinline__ float2 twid512(int idx){
    float ang = 0.012271846303085129f * (float)idx;   // 2*pi/512
    return cis_native(INV ? ang : -ang);
}

__device__ __forceinline__ unsigned int pack2bf(float x, float y){
    unsigned int ux = __float_as_uint(x);
    ux = (ux + 0x7FFFu + ((ux >> 16) & 1u)) >> 16;
    unsigned int uy = __float_as_uint(y);
    uy = (uy + 0x7FFFu + ((uy >> 16) & 1u)) & 0xFFFF0000u;
    return ux | uy;
}

// ---------------- cvt: f32 -> bf16 (RNE), vectorized ----------------------
__global__ __launch_bounds__(256) void cvt_bf16(const float4* __restrict__ src,
                                                uint2* __restrict__ dst, int n4){
    int i = blockIdx.x*256 + threadIdx.x;
    if (i < n4){
        float4 v = src[i];
        dst[i] = make_uint2(pack2bf(v.x, v.y), pack2bf(v.z, v.w));
    }
}

// ---------------- Kernel A: P = inputs @ w_ih^T, 64x64 tile ---------------
// 2048 blocks (8/CU), BK=64, 4 waves (2x2, 32x32 out each), XOR-swizzled LDS.
// PRE=true: operands already bf16 in d_ws (staging = pure 16B copies).
template<bool PRE>
__global__ __launch_bounds__(256) void gemm64(const void* __restrict__ Asrc,
                                              const void* __restrict__ Wsrc,
                                              float* __restrict__ P){
    __shared__ __align__(16) char smem[2*64*64*2];   // 16 KiB
    char* As = smem;
    char* Bs = smem + 8192;
    const int tid  = threadIdx.x;
    const int lane = tid & 63, wv = tid >> 6;
    const int wm = wv >> 1, wn = wv & 1;
    const int bm = blockIdx.y, bn = blockIdx.x;
    const int sr = tid >> 2, qc = tid & 3;     // stage: row 0..63, quarter 0..3
    const int ssw = (sr & 7) << 4;
    const int soff = (sr << 7) + (qc << 5);

    f32x4 acc[2][2] = {};
    const int frow = lane & 15;
    const int kq   = (lane >> 4) << 4;

    for (int kb = 0; kb < NIN; kb += 64){
        if (kb) __syncthreads();
        if constexpr (PRE){
            const int4* Ag = (const int4*)((const unsigned short*)Asrc + (size_t)(bm*64 + sr)*NIN + kb + qc*16);
            const int4* Wg = (const int4*)((const unsigned short*)Wsrc + (size_t)(bn*64 + sr)*NIN + kb + qc*16);
            *(int4*)(As + ( soff       ^ ssw)) = Ag[0];
            *(int4*)(As + ((soff + 16) ^ ssw)) = Ag[1];
            *(int4*)(Bs + ( soff       ^ ssw)) = Wg[0];
            *(int4*)(Bs + ((soff + 16) ^ ssw)) = Wg[1];
        } else {
            const float* Ag = (const float*)Asrc + (size_t)(bm*64 + sr)*NIN + kb + qc*16;
            const float* Wg = (const float*)Wsrc + (size_t)(bn*64 + sr)*NIN + kb + qc*16;
            float4 a0 = *(const float4*)Ag,     a1 = *(const float4*)(Ag+4);
            float4 a2 = *(const float4*)(Ag+8), a3 = *(const float4*)(Ag+12);
            float4 w0 = *(const float4*)Wg,     w1 = *(const float4*)(Wg+4);
            float4 w2 = *(const float4*)(Wg+8), w3 = *(const float4*)(Wg+12);
            int4 pa0 = make_int4((int)pack2bf(a0.x,a0.y),(int)pack2bf(a0.z,a0.w),
                                 (int)pack2bf(a1.x,a1.y),(int)pack2bf(a1.z,a1.w));
            int4 pa1 = make_int4((int)pack2bf(a2.x,a2.y),(int)pack2bf(a2.z,a2.w),
                                 (int)pack2bf(a3.x,a3.y),(int)pack2bf(a3.z,a3.w));
            int4 pw0 = make_int4((int)pack2bf(w0.x,w0.y),(int)pack2bf(w0.z,w0.w),
                                 (int)pack2bf(w1.x,w1.y),(int)pack2bf(w1.z,w1.w));
            int4 pw1 = make_int4((int)pack2bf(w2.x,w2.y),(int)pack2bf(w2.z,w2.w),
                                 (int)pack2bf(w3.x,w3.y),(int)pack2bf(w3.z,w3.w));
            *(int4*)(As + ( soff       ^ ssw)) = pa0;
            *(int4*)(As + ((soff + 16) ^ ssw)) = pa1;
            *(int4*)(Bs + ( soff       ^ ssw)) = pw0;
            *(int4*)(Bs + ((soff + 16) ^ ssw)) = pw1;
        }
        __syncthreads();
        #pragma unroll
        for (int ks = 0; ks < 2; ++ks){
            const int koff = kq + (ks << 6);
            bf16x8 a[2], b[2];
            #pragma unroll
            for (int i = 0; i < 2; ++i){
                const int ar = wm*32 + i*16 + frow;
                a[i] = *(const bf16x8*)(As + (((ar << 7) + koff) ^ ((ar & 7) << 4)));
                const int br = wn*32 + i*16 + frow;
                b[i] = *(const bf16x8*)(Bs + (((br << 7) + koff) ^ ((br & 7) << 4)));
            }
            #pragma unroll
            for (int mi = 0; mi < 2; ++mi)
                #pragma unroll
                for (int ni = 0; ni < 2; ++ni)
                    acc[mi][ni] = __builtin_amdgcn_mfma_f32_16x16x32_bf16(
                        a[mi], b[ni], acc[mi][ni], 0, 0, 0);
        }
    }

    // epilogue: stage 32-row halves through LDS, coalesced float4 writes
    float* stg = (float*)smem;                 // 32 x 68 floats = 8.7 KB
    const int lr4 = (lane >> 4) << 2;
    #pragma unroll
    for (int p = 0; p < 2; ++p){
        __syncthreads();
        if (wm == p){
            #pragma unroll
            for (int i = 0; i < 2; ++i)
                #pragma unroll
                for (int j = 0; j < 2; ++j)
                    #pragma unroll
                    for (int r = 0; r < 4; ++r)
                        stg[(i*16 + lr4 + r)*68 + wn*32 + j*16 + frow] = acc[i][j][r];
        }
        __syncthreads();
        #pragma unroll
        for (int it = 0; it < 2; ++it){
            int idx = it*256 + tid;            // 0..511: 32 rows x 16 float4
            int r32 = idx >> 4, c4 = idx & 15;
            float4 v = *(const float4*)(stg + r32*68 + c4*4);
            *(float4*)(P + (size_t)(bm*64 + p*32 + r32)*1024 + bn*64 + c4*4) = v;
        }
    }
}

// ---------------- Kernel B: 2 rows per wave (ILP-doubled) -----------------
// Twiddles / diag-cis / reflection vectors / |v|^2 shared between the rows.

__device__ __forceinline__ void bfly_f(float2& a, float2& b, float2 w){
    float2 t = csub(a, b);
    a = cadd(a, b);
    b = cmul(w, t);
}
__device__ __forceinline__ void bfly_i(float2& a, float2& b, float2 w){
    float2 t = cmul(w, b);
    b = csub(a, t);
    a = cadd(a, t);
}

__device__ __forceinline__ void fft_fwd2(float2 z0[8], float2 z1[8], int l){
    #pragma unroll
    for (int r = 0; r < 4; ++r){
        float2 w = twid512<false>(r*64 + l);
        bfly_f(z0[r], z0[r+4], w);
        bfly_f(z1[r], z1[r+4], w);
    }
    {
        float2 w0 = twid512<false>(2*l), w1 = twid512<false>(2*(64+l));
        const int gs[4] = {0,1,4,5};
        #pragma unroll
        for (int k = 0; k < 4; ++k){
            int g = gs[k];
            float2 w = (g & 1) ? w1 : w0;
            bfly_f(z0[g], z0[g+2], w);
            bfly_f(z1[g], z1[g+2], w);
        }
    }
    {
        float2 w = twid512<false>(4*l);
        #pragma unroll
        for (int g = 0; g < 8; g += 2){
            bfly_f(z0[g], z0[g+1], w);
            bfly_f(z1[g], z1[g+1], w);
        }
    }
    #pragma unroll
    for (int h = 32; h >= 1; h >>= 1){
        int m = 256 / h;
        float2 w = twid512<false>(m * (l & (h-1)));
        bool low = (l & h) != 0;
        #pragma unroll
        for (int r = 0; r < 8; ++r){
            float2 p0, p1;
            p0.x = __shfl_xor(z0[r].x, h);
            p0.y = __shfl_xor(z0[r].y, h);
            p1.x = __shfl_xor(z1[r].x, h);
            p1.y = __shfl_xor(z1[r].y, h);
            z0[r] = low ? cmul(w, csub(p0, z0[r])) : cadd(z0[r], p0);
            z1[r] = low ? cmul(w, csub(p1, z1[r])) : cadd(z1[r], p1);
        }
    }
}

__device__ __forceinline__ void fft_inv2(float2 z0[8], float2 z1[8], int l){
    #pragma unroll
    for (int h = 1; h <= 32; h <<= 1){
        int m = 256 / h;
        float2 w = twid512<true>(m * (l & (h-1)));
        bool low = (l & h) != 0;
        #pragma unroll
        for (int r = 0; r < 8; ++r){
            float2 p0, p1;
            p0.x = __shfl_xor(z0[r].x, h);
            p0.y = __shfl_xor(z0[r].y, h);
            p1.x = __shfl_xor(z1[r].x, h);
            p1.y = __shfl_xor(z1[r].y, h);
            float2 t0 = cmul(w, low ? z0[r] : p0);
            float2 t1 = cmul(w, low ? z1[r] : p1);
            z0[r] = low ? csub(p0, t0) : cadd(z0[r], t0);
            z1[r] = low ? csub(p1, t1) : cadd(z1[r], t1);
        }
    }
    {
        float2 w = twid512<true>(4*l);
        #pragma unroll
        for (int g = 0; g < 8; g += 2){
            bfly_i(z0[g], z0[g+1], w);
            bfly_i(z1[g], z1[g+1], w);
        }
    }
    {
        float2 w0 = twid512<true>(2*l), w1 = twid512<true>(2*(64+l));
        const int gs[4] = {0,1,4,5};
        #pragma unroll
        for (int k = 0; k < 4; ++k){
            int g = gs[k];
            float2 w = (g & 1) ? w1 : w0;
            bfly_i(z0[g], z0[g+2], w);
            bfly_i(z1[g], z1[g+2], w);
        }
    }
    #pragma unroll
    for (int r = 0; r < 4; ++r){
        float2 w = twid512<true>(r*64 + l);
        bfly_i(z0[r], z0[r+4], w);
        bfly_i(z1[r], z1[r+4], w);
    }
}

__device__ __forceinline__ void wave_reflect2(float2 z0[8], float2 z1[8],
                                              const float2 v[8]){
    float pr0=0.f, pi0=0.f, pr1=0.f, pi1=0.f, nn=0.f;
    #pragma unroll
    for (int r = 0; r < 8; ++r){
        pr0 += v[r].x*z0[r].x + v[r].y*z0[r].y;
        pi0 += v[r].x*z0[r].y - v[r].y*z0[r].x;
        pr1 += v[r].x*z1[r].x + v[r].y*z1[r].y;
        pi1 += v[r].x*z1[r].y - v[r].y*z1[r].x;
        nn  += v[r].x*v[r].x + v[r].y*v[r].y;
    }
    #pragma unroll
    for (int off = 32; off > 0; off >>= 1){
        pr0 += __shfl_xor(pr0, off);
        pi0 += __shfl_xor(pi0, off);
        pr1 += __shfl_xor(pr1, off);
        pi1 += __shfl_xor(pi1, off);
        nn  += __shfl_xor(nn, off);
    }
    float c2 = 2.0f / nn;
    float2 cc0 = make_float2(c2*pr0, c2*pi0);
    float2 cc1 = make_float2(c2*pr1, c2*pi1);
    #pragma unroll
    for (int r = 0; r < 8; ++r){
        z0[r] = csub(z0[r], cmul(cc0, v[r]));
        z1[r] = csub(z1[r], cmul(cc1, v[r]));
    }
}

__global__ __launch_bounds__(256, 4) void urnn_wave2(
        const float* __restrict__ states,
        const float* __restrict__ b_h,
        const float* __restrict__ d1_w,
        const float* __restrict__ r1_re, const float* __restrict__ r1_im,
        const int* __restrict__ perm,
        const float* __restrict__ d2_w,
        const float* __restrict__ r2_re, const float* __restrict__ r2_im,
        const float* __restrict__ d3_w,
        float* __restrict__ out /* in: inputs_mul, out: result */)
{
    __shared__ float2 zbuf[4][2][512];       // per-wave, per-row perm buffers

    const int tid = threadIdx.x;
    const int l = tid & 63, wv = tid >> 6;

    const int rp = (blockIdx.x*4 + wv)*2;    // row pair
    const float* s0 = states + (size_t)rp * 1024;
    const float* s1 = s0 + 1024;
    float* o0 = out + (size_t)rp * 1024;
    float* o1 = o0 + 1024;

    // state load + diag1 (cis shared between rows)
    float2 z0[8], z1[8];
    #pragma unroll
    for (int r = 0; r < 8; ++r){
        int e = r*64 + l;
        float2 d = cis_native(d1_w[e]);
        z0[r] = cmul(d, ((const float2*)s0)[e]);
        z1[r] = cmul(d, ((const float2*)s1)[e]);
    }

    fft_fwd2(z0, z1, l);           // -> storage s holds X[rev(s)]

    { // reflection 1 in bit-reversed domain (v shared)
        float2 v[8];
        #pragma unroll
        for (int r = 0; r < 8; ++r){
            int i = __brev((unsigned)(r*64 + l)) >> 23;
            v[r] = make_float2(r1_re[i], r1_im[i]);
        }
        wave_reflect2(z0, z1, v);
    }

    // permutation + diag2 (gather index + cis shared)
    {
        float2* zw0 = zbuf[wv][0];
        float2* zw1 = zbuf[wv][1];
        #pragma unroll
        for (int r = 0; r < 8; ++r){
            zw0[r*64 + l] = z0[r];
            zw1[r*64 + l] = z1[r];
        }
        // no barrier: buffers are private to this wave
        #pragma unroll
        for (int r = 0; r < 8; ++r){
            int s = r*64 + l;
            int i = __brev((unsigned)s) >> 23;
            int g = __brev((unsigned)perm[i]) >> 23;
            float2 d = cis_native(d2_w[i]);
            z0[r] = cmul(d, zw0[g]);
            z1[r] = cmul(d, zw1[g]);
        }
    }

    fft_inv2(z0, z1, l);           // -> natural order

    // preload inputs_mul now (latency hides under reflection 2)
    float2 c0[8], c1[8];
    #pragma unroll
    for (int r = 0; r < 8; ++r){
        c0[r] = ((const float2*)o0)[r*64 + l];
        c1[r] = ((const float2*)o1)[r*64 + l];
    }

    { // reflection 2 in natural domain (v shared, coalesced)
        float2 v[8];
        #pragma unroll
        for (int r = 0; r < 8; ++r){
            int e = r*64 + l;
            v[r] = make_float2(r2_re[e], r2_im[e]);
        }
        wave_reflect2(z0, z1, v);
    }

    // diag3 * (1/512) + inputs_mul + modReLU; write concat([re, im])
    const float inv = 1.0f/512.0f;
    #pragma unroll
    for (int r = 0; r < 8; ++r){
        int e = r*64 + l;
        float2 d = cis_native(d3_w[e]);
        float bh = b_h[e];
        {
            float2 zz = cmul(d, z0[r]);
            float2 pre = make_float2(c0[r].x + zz.x*inv, c0[r].y + zz.y*inv);
            float nrm = __builtin_amdgcn_sqrtf(pre.x*pre.x + pre.y*pre.y);
            float sc = fmaxf(nrm + bh, 0.f) / (nrm + 1e-6f);
            o0[e]       = sc*pre.x;
            o0[e + 512] = sc*pre.y;
        }
        {
            float2 zz = cmul(d, z1[r]);
            float2 pre = make_float2(c1[r].x + zz.x*inv, c1[r].y + zz.y*inv);
            float nrm = __builtin_amdgcn_sqrtf(pre.x*pre.x + pre.y*pre.y);
            float sc = fmaxf(nrm + bh, 0.f) / (nrm + 1e-6f);
            o1[e]       = sc*pre.x;
            o1[e + 512] = sc*pre.y;
        }
    }
}

extern "C" void kernel_launch(void* const* d_in, const int* in_sizes, int n_in,
                              void* d_out, int out_size, void* d_ws, size_t ws_size,
                              hipStream_t stream) {
    const float* inputs = (const float*)d_in[0];
    const float* states = (const float*)d_in[1];
    const float* w_ih   = (const float*)d_in[2];
    const float* b_h    = (const float*)d_in[3];
    const float* d1_w   = (const float*)d_in[4];
    const float* r1_re  = (const float*)d_in[5];
    const float* r1_im  = (const float*)d_in[6];
    const int*   perm   = (const int*)d_in[7];
    const float* d2_w   = (const float*)d_in[8];
    const float* r2_re  = (const float*)d_in[9];
    const float* r2_im  = (const float*)d_in[10];
    const float* d3_w   = (const float*)d_in[11];
    float* out = (float*)d_out;

    const size_t needA = (size_t)BATCH * NIN * 2;        // 4 MiB
    const size_t needW = (size_t)(2*NU) * NIN * 2;       // 0.5 MiB
    dim3 gA(16, 128);   // 1024/64 cols, 8192/64 rows

    if (ws_size >= needA + needW){
        unsigned short* Abf = (unsigned short*)d_ws;
        unsigned short* Wbf = (unsigned short*)((char*)d_ws + needA);
        cvt_bf16<<<(BATCH*NIN/4 + 255)/256, 256, 0, stream>>>(
            (const float4*)inputs, (uint2*)Abf, BATCH*NIN/4);
        cvt_bf16<<<(2*NU*NIN/4 + 255)/256, 256, 0, stream>>>(
            (const float4*)w_ih, (uint2*)Wbf, 2*NU*NIN/4);
        gemm64<true><<<gA, 256, 0, stream>>>(Abf, Wbf, out);
    } else {
        gemm64<false><<<gA, 256, 0, stream>>>(inputs, w_ih, out);
    }
    urnn_wave2<<<BATCH/8, 256, 0, stream>>>(states, b_h, d1_w, r1_re, r1_im,
                                            perm, d2_w, r2_re, r2_im, d3_w, out);
}